// Round 7
// baseline (479.788 us; speedup 1.0000x reference)
//
#include <hip/hip_runtime.h>

// CvT block, MI355X bf16-MFMA implementation.
// B=32, C=128, L=32 (seq=1024), H=8, DK=64, HD=512, NLAYER=4.
// R17: occupancy 2->3 at CONSTANT per-wave work (the experiment R14 didn't
// run: it halved work/wave along with raising occupancy). 4 qt/wave, grid
// 1024, simple dbuf+__syncthreads (R16 proved counted-vmcnt is neutral),
// bias = 16KB Q4 b128 table (R14-verified reads) -> LDS 48KB -> 3 blocks/CU;
// launch_bounds(256,3) caps VGPR ~170 >= measured 120 demand (R12) -> no
// spill expected (tripwire: WRITE_SIZE must stay 32768).
// CORRECTNESS FIX vs R16: LDB restores the (qt>>1) dxx term for qt=2,3
// (eh = ee + (qt>>1); R16's version was off-by-one-dxx for half the queries,
// hidden under the absmax tolerance).

#define NB   32
#define NH   8
#define SEQ  1024
#define DKH  64
#define HDIM 512
#define CIN  128

// 0.125 * log2(e): folded into Wq and bias so scores are in exp2 domain.
#define SCL 0.18033688011112042f

typedef __bf16 bf16x8 __attribute__((ext_vector_type(8)));
typedef float floatx4 __attribute__((ext_vector_type(4)));
typedef unsigned short u16x8 __attribute__((ext_vector_type(8)));
typedef unsigned int uintx4 __attribute__((ext_vector_type(4)));

__device__ __forceinline__ unsigned short f2bf(float f) {
    union { float f; unsigned int u; } c; c.f = f;
    unsigned int u = c.u;
    return (unsigned short)((u + 0x7fffu + ((u >> 16) & 1u)) >> 16); // RNE
}
__device__ __forceinline__ bf16x8 ldfrag(const unsigned short* p) {
    u16x8 v = *reinterpret_cast<const u16x8*>(p);
    return __builtin_bit_cast(bf16x8, v);
}
// pack two f32 -> two RNE bf16; 'a' lands in the LOW short.
__device__ __forceinline__ unsigned int pkbf(float a, float b) {
    unsigned int ua = __builtin_bit_cast(unsigned int, a);
    unsigned int ub = __builtin_bit_cast(unsigned int, b);
    ua += 0x7fffu + ((ua >> 16) & 1u);
    ub += 0x7fffu + ((ub >> 16) & 1u);
    return __builtin_amdgcn_perm(ub, ua, 0x07060302u);
}
// truncation pack (P>0): one v_perm, no rounding adds.
__device__ __forceinline__ unsigned int pkbf_t(float a, float b) {
    return __builtin_amdgcn_perm(__builtin_bit_cast(unsigned int, b),
                                 __builtin_bit_cast(unsigned int, a), 0x07060302u);
}
// async global->LDS, 16B per lane; LDS dest = wave-uniform base + lane*16.
__device__ __forceinline__ void g2l16(const void* g, void* l) {
    __builtin_amdgcn_global_load_lds((const __attribute__((address_space(1))) void*)g,
                                     (__attribute__((address_space(3))) void*)l, 16, 0, 0);
}

// Fragment-order storage: 512-elem block = one wave fragment [lane][j].
// Kf (A-frag, m=key): frag (s,c): lane (q,n) j <-> K[key=16s+n][d=32c+8q+j]
// Vf (A-frag, m=d, permuted k): frag (u,c): lane (q,n) jj <->
//     V[key = 32c+16(jj>>2)+4q+(jj&3)][d=16u+n]   (matches P^T pack order)

// ---------------- merged prep: bias Q4 table + weight casts + x transpose ----------------
// bids [0, 32): biasQ4[h][dxx][st][r] = R[h][dxx][(32-st-r)&31] * SCL
//   (pre-grouped float4 circulant rows; bias C-frag = Q4[dxx][st]).
// bids [32, 1056): weight casts; Wq scaled by SCL (exp2 domain).
// bids [1056, 2080): xt2 = x transposed+scaled into B/A fragment order.
__global__ __launch_bounds__(256) void prep_all(const float* __restrict__ Wq,
                                                const float* __restrict__ Wk,
                                                const float* __restrict__ Wv,
                                                const float* __restrict__ W0,
                                                const float* __restrict__ R,
                                                const float* __restrict__ x,
                                                unsigned short* __restrict__ w2,
                                                unsigned short* __restrict__ w0f,
                                                float* __restrict__ biasQ4,
                                                unsigned short* __restrict__ xt2) {
    __shared__ float lds[64 * 65];
    int bid = blockIdx.x;
    if (bid < 32) {
        int idx4 = bid * 256 + threadIdx.x;            // [0, 8192) float4 slots
        int st = idx4 & 31, dxx = (idx4 >> 5) & 31, h = idx4 >> 10;
        const float* Rh = R + (h << 10) + (dxx << 5);
        floatx4 v;
        for (int r = 0; r < 4; ++r) v[r] = Rh[(32 - st - r) & 31] * SCL;
        *(floatx4*)&biasQ4[(size_t)idx4 * 4] = v;
    } else if (bid < 1056) {
        int idx = (bid - 32) * 256 + threadIdx.x;      // [0, 262144)
        if (idx < 196608) {
            int row = idx >> 7, col = idx & 127;
            float v;
            if (row < 512)       v = Wq[idx] * SCL;
            else if (row < 1024) v = Wk[idx - 65536];
            else                 v = Wv[idx - 131072];
            int rt = row >> 4, nr = row & 15, kc = col >> 5, qc = (col & 31) >> 3, jc = col & 7;
            w2[((rt * 4 + kc) * 512) + (qc * 16 + nr) * 8 + jc] = f2bf(v);
        } else {
            int idx2 = idx - 196608;
            int row = idx2 >> 9, col = idx2 & 511;
            int rt = row >> 4, nr = row & 15, kcA = col >> 5, qc = (col & 31) >> 3, jc = col & 7;
            w0f[((rt * 16 + kcA) * 512) + (qc * 16 + nr) * 8 + jc] = f2bf(W0[idx2]);
        }
    } else {
        int r = bid - 1056;                            // [0, 1024)
        int b = r & 31, yy = (r >> 5) & 1, zz = r >> 6;
        int c0 = yy * 64, p0 = zz * 64;
        int t = threadIdx.x, tr = t >> 6, tc = t & 63;
        const float inv_layer = 0.44721359549995793f;  // 1/sqrt(5)
        for (int rr = 0; rr < 16; ++rr) {
            int cl = rr * 4 + tr;
            lds[cl * 65 + tc] = x[(b * CIN + c0 + cl) * SEQ + p0 + tc];
        }
        __syncthreads();
        for (int rr = 0; rr < 16; ++rr) {
            int pl = rr * 4 + tr;
            int pos = p0 + pl, c = c0 + tc;
            int pt = pos >> 4, np = pos & 15, kc = c >> 5, qc = (c & 31) >> 3, jc = c & 7;
            xt2[((size_t)((b * 64 + pt) * 4 + kc) * 512) + (qc * 16 + np) * 8 + jc] =
                f2bf(lds[tc * 65 + pl] * inv_layer);
        }
    }
}

// ---------------- fused QKV projection ----------------
__global__ __launch_bounds__(256, 4) void qkv_gemm(const unsigned short* __restrict__ xt2,
                                                   const unsigned short* __restrict__ w2,
                                                   unsigned short* __restrict__ Qt,
                                                   unsigned short* __restrict__ Kf,
                                                   unsigned short* __restrict__ Vf) {
    int b = blockIdx.x, y = blockIdx.y, zt = blockIdx.z;
    int tid = threadIdx.x, wave = tid >> 6, lane = tid & 63, q = lane >> 4, n = lane & 15;
    floatx4 acc[4];
    for (int s = 0; s < 4; ++s) acc[s] = (floatx4){0.f, 0.f, 0.f, 0.f};
    bf16x8 af[4], bfr[4][4];
    if (y < 16) {
        int rt = y * 4 + wave;                       // wrow tile
        const unsigned short* wbase = w2 + (size_t)rt * 4 * 512 + lane * 8;
        const unsigned short* xbase = xt2 + (size_t)(b * 64 + zt * 4) * 4 * 512 + lane * 8;
        for (int kc = 0; kc < 4; ++kc) af[kc] = ldfrag(wbase + kc * 512);
        for (int s = 0; s < 4; ++s)
            for (int kc = 0; kc < 4; ++kc) bfr[s][kc] = ldfrag(xbase + (s * 4 + kc) * 512);
        for (int kc = 0; kc < 4; ++kc)
            for (int s = 0; s < 4; ++s)
                acc[s] = __builtin_amdgcn_mfma_f32_16x16x32_bf16(af[kc], bfr[s][kc], acc[s], 0, 0, 0);
        int wrow0 = y * 64 + wave * 16;
        int pos0 = zt * 64;
        if (y < 8) {
            int h = wrow0 >> 6;
            int d0 = (wrow0 & 63) + 4 * q;
            for (int s = 0; s < 4; ++s) {
                uint2 pk;
                pk.x = pkbf(acc[s][0], acc[s][1]);
                pk.y = pkbf(acc[s][2], acc[s][3]);
                int pos = pos0 + 16 * s + n;
                *(uint2*)&Qt[((size_t)(b * NH + h) * SEQ + pos) * DKH + d0] = pk;
            }
        } else {
            // K: d = wave*16+4q+r (regs), key = 16s+n. A-frag store.
            int h = (wrow0 >> 6) - 8;
            int bh = b * NH + h;
            int cd = wave >> 1;
            int qk = 2 * (wave & 1) + (q >> 1);
            int jk = 4 * (q & 1);
            for (int s = 0; s < 4; ++s) {
                uint2 pk;
                pk.x = pkbf(acc[s][0], acc[s][1]);
                pk.y = pkbf(acc[s][2], acc[s][3]);
                size_t addr = ((size_t)(bh * 16 + zt) * 8 + s * 2 + cd) * 512
                              + (qk * 16 + n) * 8 + jk;
                *(uint2*)&Kf[addr] = pk;
            }
        }
    } else {
        int pt = zt * 4 + wave;                      // pos tile
        const unsigned short* xbase = xt2 + (size_t)((b * 64 + pt) * 4) * 512 + lane * 8;
        int rtv0 = 64 + (y - 16) * 4;                // V wrow tiles start at row 1024
        const unsigned short* wbase = w2 + (size_t)rtv0 * 4 * 512 + lane * 8;
        for (int kc = 0; kc < 4; ++kc) af[kc] = ldfrag(xbase + kc * 512);
        for (int s = 0; s < 4; ++s)
            for (int kc = 0; kc < 4; ++kc) bfr[s][kc] = ldfrag(wbase + (s * 4 + kc) * 512);
        for (int kc = 0; kc < 4; ++kc)
            for (int s = 0; s < 4; ++s)
                acc[s] = __builtin_amdgcn_mfma_f32_16x16x32_bf16(af[kc], bfr[s][kc], acc[s], 0, 0, 0);
        // V: key = wave*16+4q+r (regs) -> Vf A-frag with PV k-permutation.
        int vrow0 = (y - 16) * 64;
        int cj = wave >> 1;
        int jj0 = 4 * (wave & 1);
        for (int s = 0; s < 4; ++s) {
            int vrow = vrow0 + 16 * s + n;
            int h = vrow >> 6, d = vrow & 63;
            int u = d >> 4, nl = d & 15;
            uint2 pk;
            pk.x = pkbf(acc[s][0], acc[s][1]);
            pk.y = pkbf(acc[s][2], acc[s][3]);
            size_t addr = ((size_t)((b * NH + h) * 16 + zt) * 8 + u * 2 + cj) * 512
                          + (q * 16 + nl) * 8 + jj0;
            *(uint2*)&Vf[addr] = pk;
        }
    }
}

// ---------------- attention (4 qt/wave, 3 blocks/CU) ----------------
// WG = 256 queries (4 waves x 4 tiles of 16); key tiles of 64; grid 1024;
// one head per XCD. S^T = K Q^T with bias C-init = b128 reads from the
// per-head 16KB Q4 table in LDS (3 dxx bases: eh=ee+(qt>>1), el=eh-1);
// P^T packed in regs; O^T = V^T P^T; l = scalar lsum + epilogue shfl.
// K/V double-buffered via g2l16; ONE __syncthreads per key tile.
__global__ __launch_bounds__(256, 3) void attn_kernel(const unsigned short* __restrict__ Qt,
                                                      const unsigned short* __restrict__ Kf,
                                                      const unsigned short* __restrict__ Vf,
                                                      const float* __restrict__ biasQ4,
                                                      unsigned short* __restrict__ att2) {
    __shared__ alignas(16) unsigned short lds_k[2][8 * 512];   // 16 KB
    __shared__ alignas(16) unsigned short lds_v[2][8 * 512];   // 16 KB
    __shared__ alignas(16) float lds_bQ[4096];                 // 16 KB Q4 table

    int gid = blockIdx.x;
    int bh = gid & 255, qb = gid >> 8;                // qb in [0,4)
    int b = bh >> 3, h = bh & 7;
    int tid = threadIdx.x, wave = tid >> 6, lane = tid & 63, q = lane >> 4, n = lane & 15;
    int i0 = qb * 256 + wave * 64;
    int ti0 = i0 >> 4;

    const unsigned short* qbase = Qt + (size_t)bh * SEQ * DKH;
    const unsigned short* kft = Kf + (size_t)bh * 16 * 4096;
    const unsigned short* vft = Vf + (size_t)bh * 16 * 4096;
    int off0 = wave * 512;

    // ---- prologue: per-head Q4 table -> LDS; stage K/V tile 0 ----
    {
        const float* bQg = biasQ4 + (size_t)h * 4096;
        for (int i = 0; i < 4; ++i) {
            int fo = i * 1024 + wave * 256;           // wave-uniform float offset
            g2l16(bQg + fo + lane * 4, &lds_bQ[fo]);
        }
        g2l16(kft + off0 + lane * 8,        &lds_k[0][off0]);
        g2l16(kft + 2048 + off0 + lane * 8, &lds_k[0][2048 + off0]);
        g2l16(vft + off0 + lane * 8,        &lds_v[0][off0]);
        g2l16(vft + 2048 + off0 + lane * 8, &lds_v[0][2048 + off0]);
    }

    // Q as B-fragments: lane (q,n): query = i0+16qt+n, d = c*32+8q+j
    bf16x8 aq[4][2];
    for (int qt = 0; qt < 4; ++qt)
        for (int c = 0; c < 2; ++c)
            aq[qt][c] = ldfrag(qbase + (i0 + 16 * qt + n) * DKH + c * 32 + q * 8);

    floatx4 o[4][4];
    float lsum[4] = {0.f, 0.f, 0.f, 0.f};
    for (int qt = 0; qt < 4; ++qt)
        for (int u = 0; u < 4; ++u) o[qt][u] = (floatx4){0.f, 0.f, 0.f, 0.f};

    // bias gather: sv_s = Q4[dxx][st] (float4 = one b128).
    //   dxx = (ee + (qt>>1) - (s>>1)) & 31, ee = qb*8 + 2*wave - 2*kt;
    //   st = st0 if (s&1)==(qt&1) else st1 (per-lane column starts).
    int st0_4 = ((4 * q - n) & 31) * 4;
    int st1_4 = (((4 * q - n) + 16) & 31) * 4;
    int ee64 = qb * 8 + 2 * wave + 256;               // stays positive over kt

    __syncthreads();

// bias C-init for query tile qt (3 dxx bases: eh = ee+(qt>>1), el = eh-1)
#define LDB(qt, s0, s1, s2, s3) do {                                          \
        int eh_ = ee64 + ((qt) >> 1);                                         \
        int dh_ = (eh_ & 31) << 7;                                            \
        int dl_ = ((eh_ - 1) & 31) << 7;                                      \
        int sa_ = ((qt) & 1) ? st1_4 : st0_4;                                 \
        int sb_ = ((qt) & 1) ? st0_4 : st1_4;                                 \
        s0 = *(const floatx4*)&lds_bQ[dh_ + sa_];                             \
        s1 = *(const floatx4*)&lds_bQ[dh_ + sb_];                             \
        s2 = *(const floatx4*)&lds_bQ[dl_ + sa_];                             \
        s3 = *(const floatx4*)&lds_bQ[dl_ + sb_];                             \
    } while (0)

// S^T MFMA cluster for query tile qt
#define SMM(qt, s0, s1, s2, s3) do {                                          \
        s0 = __builtin_amdgcn_mfma_f32_16x16x32_bf16(kf2[0][0], aq[qt][0], s0, 0, 0, 0); \
        s0 = __builtin_amdgcn_mfma_f32_16x16x32_bf16(kf2[0][1], aq[qt][1], s0, 0, 0, 0); \
        s1 = __builtin_amdgcn_mfma_f32_16x16x32_bf16(kf2[1][0], aq[qt][0], s1, 0, 0, 0); \
        s1 = __builtin_amdgcn_mfma_f32_16x16x32_bf16(kf2[1][1], aq[qt][1], s1, 0, 0, 0); \
        s2 = __builtin_amdgcn_mfma_f32_16x16x32_bf16(kf2[2][0], aq[qt][0], s2, 0, 0, 0); \
        s2 = __builtin_amdgcn_mfma_f32_16x16x32_bf16(kf2[2][1], aq[qt][1], s2, 0, 0, 0); \
        s3 = __builtin_amdgcn_mfma_f32_16x16x32_bf16(kf2[3][0], aq[qt][0], s3, 0, 0, 0); \
        s3 = __builtin_amdgcn_mfma_f32_16x16x32_bf16(kf2[3][1], aq[qt][1], s3, 0, 0, 0); \
    } while (0)

// exp2 -> pack -> l partial -> O MFMA cluster for query tile qt
#define EPO(qt, s0, s1, s2, s3) do {                                          \
        floatx4 e0_, e1_, e2_, e3_;                                           \
        for (int r_ = 0; r_ < 4; ++r_) {                                      \
            e0_[r_] = __builtin_amdgcn_exp2f(s0[r_]);                         \
            e1_[r_] = __builtin_amdgcn_exp2f(s1[r_]);                         \
            e2_[r_] = __builtin_amdgcn_exp2f(s2[r_]);                         \
            e3_[r_] = __builtin_amdgcn_exp2f(s3[r_]);                         \
        }                                                                     \
        uintx4 pu0_, pu1_;                                                    \
        pu0_[0] = pkbf_t(e0_[0], e0_[1]);                                     \
        pu0_[1] = pkbf_t(e0_[2], e0_[3]);                                     \
        pu0_[2] = pkbf_t(e1_[0], e1_[1]);                                     \
        pu0_[3] = pkbf_t(e1_[2], e1_[3]);                                     \
        pu1_[0] = pkbf_t(e2_[0], e2_[1]);                                     \
        pu1_[1] = pkbf_t(e2_[2], e2_[3]);                                     \
        pu1_[2] = pkbf_t(e3_[0], e3_[1]);                                     \
        pu1_[3] = pkbf_t(e3_[2], e3_[3]);                                     \
        bf16x8 pf0_ = __builtin_bit_cast(bf16x8, pu0_);                       \
        bf16x8 pf1_ = __builtin_bit_cast(bf16x8, pu1_);                       \
        floatx4 es_ = (e0_ + e1_) + (e2_ + e3_);                              \
        lsum[qt] += (es_[0] + es_[1]) + (es_[2] + es_[3]);                    \
        o[qt][0] = __builtin_amdgcn_mfma_f32_16x16x32_bf16(vf2[0][0], pf0_, o[qt][0], 0, 0, 0); \
        o[qt][0] = __builtin_amdgcn_mfma_f32_16x16x32_bf16(vf2[0][1], pf1_, o[qt][0], 0, 0, 0); \
        o[qt][1] = __builtin_amdgcn_mfma_f32_16x16x32_bf16(vf2[1][0], pf0_, o[qt][1], 0, 0, 0); \
        o[qt][1] = __builtin_amdgcn_mfma_f32_16x16x32_bf16(vf2[1][1], pf1_, o[qt][1], 0, 0, 0); \
        o[qt][2] = __builtin_amdgcn_mfma_f32_16x16x32_bf16(vf2[2][0], pf0_, o[qt][2], 0, 0, 0); \
        o[qt][2] = __builtin_amdgcn_mfma_f32_16x16x32_bf16(vf2[2][1], pf1_, o[qt][2], 0, 0, 0); \
        o[qt][3] = __builtin_amdgcn_mfma_f32_16x16x32_bf16(vf2[3][0], pf0_, o[qt][3], 0, 0, 0); \
        o[qt][3] = __builtin_amdgcn_mfma_f32_16x16x32_bf16(vf2[3][1], pf1_, o[qt][3], 0, 0, 0); \
    } while (0)

    for (int kt = 0; kt < 16; ++kt) {
        int cur = kt & 1;

        // async stage next K/V tile
        if (kt < 15) {
            const unsigned short* kg = kft + (kt + 1) * 4096;
            const unsigned short* vg = vft + (kt + 1) * 4096;
            unsigned short* dk = &lds_k[cur ^ 1][0];
            unsigned short* dv = &lds_v[cur ^ 1][0];
            g2l16(kg + off0 + lane * 8,        dk + off0);
            g2l16(kg + 2048 + off0 + lane * 8, dk + 2048 + off0);
            g2l16(vg + off0 + lane * 8,        dv + off0);
            g2l16(vg + 2048 + off0 + lane * 8, dv + 2048 + off0);
        }

        // K,V fragments (shared across the 4 query tiles)
        bf16x8 kf2[4][2], vf2[4][2];
#pragma unroll
        for (int s = 0; s < 4; ++s)
#pragma unroll
            for (int c = 0; c < 2; ++c) {
                kf2[s][c] = ldfrag(&lds_k[cur][(s * 2 + c) * 512 + lane * 8]);
                vf2[s][c] = ldfrag(&lds_v[cur][(s * 2 + c) * 512 + lane * 8]);
            }

        floatx4 s0, s1, s2, s3;
        LDB(0, s0, s1, s2, s3);
        SMM(0, s0, s1, s2, s3);
        EPO(0, s0, s1, s2, s3);
        LDB(1, s0, s1, s2, s3);
        SMM(1, s0, s1, s2, s3);
        EPO(1, s0, s1, s2, s3);
        LDB(2, s0, s1, s2, s3);
        SMM(2, s0, s1, s2, s3);
        EPO(2, s0, s1, s2, s3);
        LDB(3, s0, s1, s2, s3);
        SMM(3, s0, s1, s2, s3);
        EPO(3, s0, s1, s2, s3);

        ee64 -= 2;
        __syncthreads();   // drains staged global_load_lds for kt+1 too
    }

#undef LDB
#undef SMM
#undef EPO

    // epilogue: reduce l across q-groups; O^T lane (q,n): query = i0+16qt+n,
    // d = 16u+4q+r -> att2 A-frag
    for (int qt = 0; qt < 4; ++qt) {
        float ls = lsum[qt];
        ls += __shfl_xor(ls, 16, 64);
        ls += __shfl_xor(ls, 32, 64);
        float inv = 1.0f / ls;
        int pt = ti0 + qt;
        for (int u = 0; u < 4; ++u) {
            int kcA = 2 * h + (u >> 1);
            int q2 = 2 * (u & 1) + (q >> 1);
            uint2 pk;
            pk.x = pkbf(o[qt][u][0] * inv, o[qt][u][1] * inv);
            pk.y = pkbf(o[qt][u][2] * inv, o[qt][u][3] * inv);
            size_t addr = ((size_t)((b * 64 + pt) * 16 + kcA) * 512)
                          + (q2 * 16 + n) * 8 + 4 * (q & 1);
            *(uint2*)&att2[addr] = pk;
        }
    }
}

// ---------------- output projection + residual ----------------
__global__ __launch_bounds__(256, 4) void out_gemm(const unsigned short* __restrict__ att2,
                                                   const unsigned short* __restrict__ w0f,
                                                   const float* __restrict__ x,
                                                   float* __restrict__ out) {
    int b = blockIdx.x, ct = blockIdx.y, ptb = blockIdx.z;
    int tid = threadIdx.x, wave = tid >> 6, lane = tid & 63, q = lane >> 4, n = lane & 15;
    int pos0 = ptb * 64 + wave * 16;
    int c0 = ct * 64;
    int pt = ptb * 4 + wave;
    const unsigned short* abase = att2 + (size_t)(b * 64 + pt) * 16 * 512 + lane * 8;
    const unsigned short* wbase = w0f + (size_t)(c0 >> 4) * 16 * 512 + lane * 8;
    floatx4 acc[4];
    for (int s = 0; s < 4; ++s) acc[s] = (floatx4){0.f, 0.f, 0.f, 0.f};
    for (int g = 0; g < 4; ++g) {
        bf16x8 af[4], bfr[4][4];
        for (int k2 = 0; k2 < 4; ++k2) af[k2] = ldfrag(abase + (g * 4 + k2) * 512);
        for (int s = 0; s < 4; ++s)
            for (int k2 = 0; k2 < 4; ++k2)
                bfr[s][k2] = ldfrag(wbase + (s * 16 + g * 4 + k2) * 512);
        for (int k2 = 0; k2 < 4; ++k2)
            for (int s = 0; s < 4; ++s)
                acc[s] = __builtin_amdgcn_mfma_f32_16x16x32_bf16(af[k2], bfr[s][k2], acc[s], 0, 0, 0);
    }
    int p0q = pos0 + 4 * q;
    for (int s = 0; s < 4; ++s) {
        int c = c0 + 16 * s + n;
        size_t idx = ((size_t)b * CIN + c) * SEQ + p0q;
        floatx4 res = *(const floatx4*)&x[idx];
        floatx4 v = acc[s] + res;
        *(floatx4*)&out[idx] = v;
    }
}

// ---------------- launch ----------------
extern "C" void kernel_launch(void* const* d_in, const int* in_sizes, int n_in,
                              void* d_out, int out_size, void* d_ws, size_t ws_size,
                              hipStream_t stream) {
    const float* x  = (const float*)d_in[0];
    const float* Wq = (const float*)d_in[1];
    const float* Wk = (const float*)d_in[2];
    const float* Wv = (const float*)d_in[3];
    const float* R  = (const float*)d_in[4];
    const float* W0 = (const float*)d_in[5];
    float* out = (float*)d_out;

    char* ws = (char*)d_ws;
    size_t off = 0;
    unsigned short* Qt   = (unsigned short*)(ws + off); off += (size_t)NB * NH * SEQ * DKH * 2;
    unsigned short* Kf   = (unsigned short*)(ws + off); off += (size_t)NB * NH * SEQ * DKH * 2;
    unsigned short* Vf   = (unsigned short*)(ws + off); off += (size_t)NB * NH * SEQ * DKH * 2;
    unsigned short* att2 = (unsigned short*)(ws + off); off += (size_t)NB * SEQ * HDIM * 2;
    unsigned short* xt2  = (unsigned short*)(ws + off); off += (size_t)NB * SEQ * CIN * 2;
    unsigned short* w2   = (unsigned short*)(ws + off); off += (size_t)1536 * 128 * 2;
    unsigned short* w0f  = (unsigned short*)(ws + off); off += (size_t)128 * 512 * 2;
    float* biasQ4 = (float*)(ws + off); off += (size_t)NH * 32 * 32 * 4 * 4;   // 128 KB
    (void)ws_size; (void)in_sizes; (void)n_in; (void)out_size;

    prep_all<<<2080, 256, 0, stream>>>(Wq, Wk, Wv, W0, R, x, w2, w0f, biasQ4, xt2);
    qkv_gemm<<<dim3(NB, 24, 16), 256, 0, stream>>>(xt2, w2, Qt, Kf, Vf);
    attn_kernel<<<NB * NH * 4, 256, 0, stream>>>(Qt, Kf, Vf, biasQ4, att2);
    out_gemm<<<dim3(NB, 2, 16), 256, 0, stream>>>(att2, w0f, x, out);
}

// Round 8
// 209.507 us; speedup vs baseline: 2.2901x; 2.2901x over previous
//
#include <hip/hip_runtime.h>

// CvT block, MI355X bf16-MFMA implementation.
// B=32, C=128, L=32 (seq=1024), H=8, DK=64, HD=512, NLAYER=4.
// R18: THE SPILL FIX. Empirical VGPR-cap rule from R12-R17: cap =
// 256/waves-per-SIMD ((256,2)->128, (256,3)->~85, (256,4)->64).
// qkv_gemm/out_gemm demand ~100-110 VGPR (af 16 + bfr 64 + acc 16 + temps)
// -> they have been SPILLING at (256,4) all session (invisible: rocprof
// top-5 only showed attn). Fix: (256,2) on both. Attn restored to its
// proven (256,2) config: 4 qt/wave, grid 1024, Q4 bias table (16KB, b128
// reads), simple dbuf + __syncthreads, scalar lsum. No other changes --
// isolate the spill variable.

#define NB   32
#define NH   8
#define SEQ  1024
#define DKH  64
#define HDIM 512
#define CIN  128

// 0.125 * log2(e): folded into Wq and bias so scores are in exp2 domain.
#define SCL 0.18033688011112042f

typedef __bf16 bf16x8 __attribute__((ext_vector_type(8)));
typedef float floatx4 __attribute__((ext_vector_type(4)));
typedef unsigned short u16x8 __attribute__((ext_vector_type(8)));
typedef unsigned int uintx4 __attribute__((ext_vector_type(4)));

__device__ __forceinline__ unsigned short f2bf(float f) {
    union { float f; unsigned int u; } c; c.f = f;
    unsigned int u = c.u;
    return (unsigned short)((u + 0x7fffu + ((u >> 16) & 1u)) >> 16); // RNE
}
__device__ __forceinline__ bf16x8 ldfrag(const unsigned short* p) {
    u16x8 v = *reinterpret_cast<const u16x8*>(p);
    return __builtin_bit_cast(bf16x8, v);
}
// pack two f32 -> two RNE bf16; 'a' lands in the LOW short.
__device__ __forceinline__ unsigned int pkbf(float a, float b) {
    unsigned int ua = __builtin_bit_cast(unsigned int, a);
    unsigned int ub = __builtin_bit_cast(unsigned int, b);
    ua += 0x7fffu + ((ua >> 16) & 1u);
    ub += 0x7fffu + ((ub >> 16) & 1u);
    return __builtin_amdgcn_perm(ub, ua, 0x07060302u);
}
// truncation pack (P>0): one v_perm, no rounding adds.
__device__ __forceinline__ unsigned int pkbf_t(float a, float b) {
    return __builtin_amdgcn_perm(__builtin_bit_cast(unsigned int, b),
                                 __builtin_bit_cast(unsigned int, a), 0x07060302u);
}
// async global->LDS, 16B per lane; LDS dest = wave-uniform base + lane*16.
__device__ __forceinline__ void g2l16(const void* g, void* l) {
    __builtin_amdgcn_global_load_lds((const __attribute__((address_space(1))) void*)g,
                                     (__attribute__((address_space(3))) void*)l, 16, 0, 0);
}

// Fragment-order storage: 512-elem block = one wave fragment [lane][j].
// Kf (A-frag, m=key): frag (s,c): lane (q,n) j <-> K[key=16s+n][d=32c+8q+j]
// Vf (A-frag, m=d, permuted k): frag (u,c): lane (q,n) jj <->
//     V[key = 32c+16(jj>>2)+4q+(jj&3)][d=16u+n]   (matches P^T pack order)

// ---------------- merged prep: bias Q4 table + weight casts + x transpose ----------------
// bids [0, 32): biasQ4[h][dxx][st][r] = R[h][dxx][(32-st-r)&31] * SCL
//   (pre-grouped float4 circulant rows; bias C-frag = Q4[dxx][st]).
// bids [32, 1056): weight casts; Wq scaled by SCL (exp2 domain).
// bids [1056, 2080): xt2 = x transposed+scaled into B/A fragment order.
__global__ __launch_bounds__(256) void prep_all(const float* __restrict__ Wq,
                                                const float* __restrict__ Wk,
                                                const float* __restrict__ Wv,
                                                const float* __restrict__ W0,
                                                const float* __restrict__ R,
                                                const float* __restrict__ x,
                                                unsigned short* __restrict__ w2,
                                                unsigned short* __restrict__ w0f,
                                                float* __restrict__ biasQ4,
                                                unsigned short* __restrict__ xt2) {
    __shared__ float lds[64 * 65];
    int bid = blockIdx.x;
    if (bid < 32) {
        int idx4 = bid * 256 + threadIdx.x;            // [0, 8192) float4 slots
        int st = idx4 & 31, dxx = (idx4 >> 5) & 31, h = idx4 >> 10;
        const float* Rh = R + (h << 10) + (dxx << 5);
        floatx4 v;
        for (int r = 0; r < 4; ++r) v[r] = Rh[(32 - st - r) & 31] * SCL;
        *(floatx4*)&biasQ4[(size_t)idx4 * 4] = v;
    } else if (bid < 1056) {
        int idx = (bid - 32) * 256 + threadIdx.x;      // [0, 262144)
        if (idx < 196608) {
            int row = idx >> 7, col = idx & 127;
            float v;
            if (row < 512)       v = Wq[idx] * SCL;
            else if (row < 1024) v = Wk[idx - 65536];
            else                 v = Wv[idx - 131072];
            int rt = row >> 4, nr = row & 15, kc = col >> 5, qc = (col & 31) >> 3, jc = col & 7;
            w2[((rt * 4 + kc) * 512) + (qc * 16 + nr) * 8 + jc] = f2bf(v);
        } else {
            int idx2 = idx - 196608;
            int row = idx2 >> 9, col = idx2 & 511;
            int rt = row >> 4, nr = row & 15, kcA = col >> 5, qc = (col & 31) >> 3, jc = col & 7;
            w0f[((rt * 16 + kcA) * 512) + (qc * 16 + nr) * 8 + jc] = f2bf(W0[idx2]);
        }
    } else {
        int r = bid - 1056;                            // [0, 1024)
        int b = r & 31, yy = (r >> 5) & 1, zz = r >> 6;
        int c0 = yy * 64, p0 = zz * 64;
        int t = threadIdx.x, tr = t >> 6, tc = t & 63;
        const float inv_layer = 0.44721359549995793f;  // 1/sqrt(5)
        for (int rr = 0; rr < 16; ++rr) {
            int cl = rr * 4 + tr;
            lds[cl * 65 + tc] = x[(b * CIN + c0 + cl) * SEQ + p0 + tc];
        }
        __syncthreads();
        for (int rr = 0; rr < 16; ++rr) {
            int pl = rr * 4 + tr;
            int pos = p0 + pl, c = c0 + tc;
            int pt = pos >> 4, np = pos & 15, kc = c >> 5, qc = (c & 31) >> 3, jc = c & 7;
            xt2[((size_t)((b * 64 + pt) * 4 + kc) * 512) + (qc * 16 + np) * 8 + jc] =
                f2bf(lds[tc * 65 + pl] * inv_layer);
        }
    }
}

// ---------------- fused QKV projection ----------------
// (256,2): VGPR cap 128 >= ~110 demand. Was (256,4) = cap 64 -> spilled.
__global__ __launch_bounds__(256, 2) void qkv_gemm(const unsigned short* __restrict__ xt2,
                                                   const unsigned short* __restrict__ w2,
                                                   unsigned short* __restrict__ Qt,
                                                   unsigned short* __restrict__ Kf,
                                                   unsigned short* __restrict__ Vf) {
    int b = blockIdx.x, y = blockIdx.y, zt = blockIdx.z;
    int tid = threadIdx.x, wave = tid >> 6, lane = tid & 63, q = lane >> 4, n = lane & 15;
    floatx4 acc[4];
    for (int s = 0; s < 4; ++s) acc[s] = (floatx4){0.f, 0.f, 0.f, 0.f};
    bf16x8 af[4], bfr[4][4];
    if (y < 16) {
        int rt = y * 4 + wave;                       // wrow tile
        const unsigned short* wbase = w2 + (size_t)rt * 4 * 512 + lane * 8;
        const unsigned short* xbase = xt2 + (size_t)(b * 64 + zt * 4) * 4 * 512 + lane * 8;
        for (int kc = 0; kc < 4; ++kc) af[kc] = ldfrag(wbase + kc * 512);
        for (int s = 0; s < 4; ++s)
            for (int kc = 0; kc < 4; ++kc) bfr[s][kc] = ldfrag(xbase + (s * 4 + kc) * 512);
        for (int kc = 0; kc < 4; ++kc)
            for (int s = 0; s < 4; ++s)
                acc[s] = __builtin_amdgcn_mfma_f32_16x16x32_bf16(af[kc], bfr[s][kc], acc[s], 0, 0, 0);
        int wrow0 = y * 64 + wave * 16;
        int pos0 = zt * 64;
        if (y < 8) {
            int h = wrow0 >> 6;
            int d0 = (wrow0 & 63) + 4 * q;
            for (int s = 0; s < 4; ++s) {
                uint2 pk;
                pk.x = pkbf(acc[s][0], acc[s][1]);
                pk.y = pkbf(acc[s][2], acc[s][3]);
                int pos = pos0 + 16 * s + n;
                *(uint2*)&Qt[((size_t)(b * NH + h) * SEQ + pos) * DKH + d0] = pk;
            }
        } else {
            // K: d = wave*16+4q+r (regs), key = 16s+n. A-frag store.
            int h = (wrow0 >> 6) - 8;
            int bh = b * NH + h;
            int cd = wave >> 1;
            int qk = 2 * (wave & 1) + (q >> 1);
            int jk = 4 * (q & 1);
            for (int s = 0; s < 4; ++s) {
                uint2 pk;
                pk.x = pkbf(acc[s][0], acc[s][1]);
                pk.y = pkbf(acc[s][2], acc[s][3]);
                size_t addr = ((size_t)(bh * 16 + zt) * 8 + s * 2 + cd) * 512
                              + (qk * 16 + n) * 8 + jk;
                *(uint2*)&Kf[addr] = pk;
            }
        }
    } else {
        int pt = zt * 4 + wave;                      // pos tile
        const unsigned short* xbase = xt2 + (size_t)((b * 64 + pt) * 4) * 512 + lane * 8;
        int rtv0 = 64 + (y - 16) * 4;                // V wrow tiles start at row 1024
        const unsigned short* wbase = w2 + (size_t)rtv0 * 4 * 512 + lane * 8;
        for (int kc = 0; kc < 4; ++kc) af[kc] = ldfrag(xbase + kc * 512);
        for (int s = 0; s < 4; ++s)
            for (int kc = 0; kc < 4; ++kc) bfr[s][kc] = ldfrag(wbase + (s * 4 + kc) * 512);
        for (int kc = 0; kc < 4; ++kc)
            for (int s = 0; s < 4; ++s)
                acc[s] = __builtin_amdgcn_mfma_f32_16x16x32_bf16(af[kc], bfr[s][kc], acc[s], 0, 0, 0);
        // V: key = wave*16+4q+r (regs) -> Vf A-frag with PV k-permutation.
        int vrow0 = (y - 16) * 64;
        int cj = wave >> 1;
        int jj0 = 4 * (wave & 1);
        for (int s = 0; s < 4; ++s) {
            int vrow = vrow0 + 16 * s + n;
            int h = vrow >> 6, d = vrow & 63;
            int u = d >> 4, nl = d & 15;
            uint2 pk;
            pk.x = pkbf(acc[s][0], acc[s][1]);
            pk.y = pkbf(acc[s][2], acc[s][3]);
            size_t addr = ((size_t)((b * NH + h) * 16 + zt) * 8 + u * 2 + cj) * 512
                          + (q * 16 + nl) * 8 + jj0;
            *(uint2*)&Vf[addr] = pk;
        }
    }
}

// ---------------- attention (4 qt/wave, 2 blocks/CU — proven config) ----------------
// WG = 256 queries (4 waves x 4 tiles of 16); key tiles of 64; grid 1024;
// one head per XCD. S^T = K Q^T with bias C-init = b128 reads from the
// per-head 16KB Q4 table in LDS (3 dxx bases: eh=ee+(qt>>1), el=eh-1);
// P^T packed in regs; O^T = V^T P^T; l = scalar lsum + epilogue shfl.
// K/V double-buffered via g2l16; ONE __syncthreads per key tile.
__global__ __launch_bounds__(256, 2) void attn_kernel(const unsigned short* __restrict__ Qt,
                                                      const unsigned short* __restrict__ Kf,
                                                      const unsigned short* __restrict__ Vf,
                                                      const float* __restrict__ biasQ4,
                                                      unsigned short* __restrict__ att2) {
    __shared__ alignas(16) unsigned short lds_k[2][8 * 512];   // 16 KB
    __shared__ alignas(16) unsigned short lds_v[2][8 * 512];   // 16 KB
    __shared__ alignas(16) float lds_bQ[4096];                 // 16 KB Q4 table

    int gid = blockIdx.x;
    int bh = gid & 255, qb = gid >> 8;                // qb in [0,4)
    int b = bh >> 3, h = bh & 7;
    int tid = threadIdx.x, wave = tid >> 6, lane = tid & 63, q = lane >> 4, n = lane & 15;
    int i0 = qb * 256 + wave * 64;
    int ti0 = i0 >> 4;

    const unsigned short* qbase = Qt + (size_t)bh * SEQ * DKH;
    const unsigned short* kft = Kf + (size_t)bh * 16 * 4096;
    const unsigned short* vft = Vf + (size_t)bh * 16 * 4096;
    int off0 = wave * 512;

    // ---- prologue: per-head Q4 table -> LDS; stage K/V tile 0 ----
    {
        const float* bQg = biasQ4 + (size_t)h * 4096;
        for (int i = 0; i < 4; ++i) {
            int fo = i * 1024 + wave * 256;           // wave-uniform float offset
            g2l16(bQg + fo + lane * 4, &lds_bQ[fo]);
        }
        g2l16(kft + off0 + lane * 8,        &lds_k[0][off0]);
        g2l16(kft + 2048 + off0 + lane * 8, &lds_k[0][2048 + off0]);
        g2l16(vft + off0 + lane * 8,        &lds_v[0][off0]);
        g2l16(vft + 2048 + off0 + lane * 8, &lds_v[0][2048 + off0]);
    }

    // Q as B-fragments: lane (q,n): query = i0+16qt+n, d = c*32+8q+j
    bf16x8 aq[4][2];
    for (int qt = 0; qt < 4; ++qt)
        for (int c = 0; c < 2; ++c)
            aq[qt][c] = ldfrag(qbase + (i0 + 16 * qt + n) * DKH + c * 32 + q * 8);

    floatx4 o[4][4];
    float lsum[4] = {0.f, 0.f, 0.f, 0.f};
    for (int qt = 0; qt < 4; ++qt)
        for (int u = 0; u < 4; ++u) o[qt][u] = (floatx4){0.f, 0.f, 0.f, 0.f};

    // bias gather: sv_s = Q4[dxx][st] (float4 = one b128).
    //   dxx = (ee + (qt>>1) - (s>>1)) & 31, ee = qb*8 + 2*wave - 2*kt;
    //   st = st0 if (s&1)==(qt&1) else st1 (per-lane column starts).
    int st0_4 = ((4 * q - n) & 31) * 4;
    int st1_4 = (((4 * q - n) + 16) & 31) * 4;
    int ee64 = qb * 8 + 2 * wave + 256;               // stays positive over kt

    __syncthreads();

// bias C-init for query tile qt (3 dxx bases: eh = ee+(qt>>1), el = eh-1)
#define LDB(qt, s0, s1, s2, s3) do {                                          \
        int eh_ = ee64 + ((qt) >> 1);                                         \
        int dh_ = (eh_ & 31) << 7;                                            \
        int dl_ = ((eh_ - 1) & 31) << 7;                                      \
        int sa_ = ((qt) & 1) ? st1_4 : st0_4;                                 \
        int sb_ = ((qt) & 1) ? st0_4 : st1_4;                                 \
        s0 = *(const floatx4*)&lds_bQ[dh_ + sa_];                             \
        s1 = *(const floatx4*)&lds_bQ[dh_ + sb_];                             \
        s2 = *(const floatx4*)&lds_bQ[dl_ + sa_];                             \
        s3 = *(const floatx4*)&lds_bQ[dl_ + sb_];                             \
    } while (0)

// S^T MFMA cluster for query tile qt
#define SMM(qt, s0, s1, s2, s3) do {                                          \
        s0 = __builtin_amdgcn_mfma_f32_16x16x32_bf16(kf2[0][0], aq[qt][0], s0, 0, 0, 0); \
        s0 = __builtin_amdgcn_mfma_f32_16x16x32_bf16(kf2[0][1], aq[qt][1], s0, 0, 0, 0); \
        s1 = __builtin_amdgcn_mfma_f32_16x16x32_bf16(kf2[1][0], aq[qt][0], s1, 0, 0, 0); \
        s1 = __builtin_amdgcn_mfma_f32_16x16x32_bf16(kf2[1][1], aq[qt][1], s1, 0, 0, 0); \
        s2 = __builtin_amdgcn_mfma_f32_16x16x32_bf16(kf2[2][0], aq[qt][0], s2, 0, 0, 0); \
        s2 = __builtin_amdgcn_mfma_f32_16x16x32_bf16(kf2[2][1], aq[qt][1], s2, 0, 0, 0); \
        s3 = __builtin_amdgcn_mfma_f32_16x16x32_bf16(kf2[3][0], aq[qt][0], s3, 0, 0, 0); \
        s3 = __builtin_amdgcn_mfma_f32_16x16x32_bf16(kf2[3][1], aq[qt][1], s3, 0, 0, 0); \
    } while (0)

// exp2 -> pack -> l partial -> O MFMA cluster for query tile qt
#define EPO(qt, s0, s1, s2, s3) do {                                          \
        floatx4 e0_, e1_, e2_, e3_;                                           \
        for (int r_ = 0; r_ < 4; ++r_) {                                      \
            e0_[r_] = __builtin_amdgcn_exp2f(s0[r_]);                         \
            e1_[r_] = __builtin_amdgcn_exp2f(s1[r_]);                         \
            e2_[r_] = __builtin_amdgcn_exp2f(s2[r_]);                         \
            e3_[r_] = __builtin_amdgcn_exp2f(s3[r_]);                         \
        }                                                                     \
        uintx4 pu0_, pu1_;                                                    \
        pu0_[0] = pkbf_t(e0_[0], e0_[1]);                                     \
        pu0_[1] = pkbf_t(e0_[2], e0_[3]);                                     \
        pu0_[2] = pkbf_t(e1_[0], e1_[1]);                                     \
        pu0_[3] = pkbf_t(e1_[2], e1_[3]);                                     \
        pu1_[0] = pkbf_t(e2_[0], e2_[1]);                                     \
        pu1_[1] = pkbf_t(e2_[2], e2_[3]);                                     \
        pu1_[2] = pkbf_t(e3_[0], e3_[1]);                                     \
        pu1_[3] = pkbf_t(e3_[2], e3_[3]);                                     \
        bf16x8 pf0_ = __builtin_bit_cast(bf16x8, pu0_);                       \
        bf16x8 pf1_ = __builtin_bit_cast(bf16x8, pu1_);                       \
        floatx4 es_ = (e0_ + e1_) + (e2_ + e3_);                              \
        lsum[qt] += (es_[0] + es_[1]) + (es_[2] + es_[3]);                    \
        o[qt][0] = __builtin_amdgcn_mfma_f32_16x16x32_bf16(vf2[0][0], pf0_, o[qt][0], 0, 0, 0); \
        o[qt][0] = __builtin_amdgcn_mfma_f32_16x16x32_bf16(vf2[0][1], pf1_, o[qt][0], 0, 0, 0); \
        o[qt][1] = __builtin_amdgcn_mfma_f32_16x16x32_bf16(vf2[1][0], pf0_, o[qt][1], 0, 0, 0); \
        o[qt][1] = __builtin_amdgcn_mfma_f32_16x16x32_bf16(vf2[1][1], pf1_, o[qt][1], 0, 0, 0); \
        o[qt][2] = __builtin_amdgcn_mfma_f32_16x16x32_bf16(vf2[2][0], pf0_, o[qt][2], 0, 0, 0); \
        o[qt][2] = __builtin_amdgcn_mfma_f32_16x16x32_bf16(vf2[2][1], pf1_, o[qt][2], 0, 0, 0); \
        o[qt][3] = __builtin_amdgcn_mfma_f32_16x16x32_bf16(vf2[3][0], pf0_, o[qt][3], 0, 0, 0); \
        o[qt][3] = __builtin_amdgcn_mfma_f32_16x16x32_bf16(vf2[3][1], pf1_, o[qt][3], 0, 0, 0); \
    } while (0)

    for (int kt = 0; kt < 16; ++kt) {
        int cur = kt & 1;

        // async stage next K/V tile
        if (kt < 15) {
            const unsigned short* kg = kft + (kt + 1) * 4096;
            const unsigned short* vg = vft + (kt + 1) * 4096;
            unsigned short* dk = &lds_k[cur ^ 1][0];
            unsigned short* dv = &lds_v[cur ^ 1][0];
            g2l16(kg + off0 + lane * 8,        dk + off0);
            g2l16(kg + 2048 + off0 + lane * 8, dk + 2048 + off0);
            g2l16(vg + off0 + lane * 8,        dv + off0);
            g2l16(vg + 2048 + off0 + lane * 8, dv + 2048 + off0);
        }

        // K,V fragments (shared across the 4 query tiles)
        bf16x8 kf2[4][2], vf2[4][2];
#pragma unroll
        for (int s = 0; s < 4; ++s)
#pragma unroll
            for (int c = 0; c < 2; ++c) {
                kf2[s][c] = ldfrag(&lds_k[cur][(s * 2 + c) * 512 + lane * 8]);
                vf2[s][c] = ldfrag(&lds_v[cur][(s * 2 + c) * 512 + lane * 8]);
            }

        floatx4 s0, s1, s2, s3;
        LDB(0, s0, s1, s2, s3);
        SMM(0, s0, s1, s2, s3);
        EPO(0, s0, s1, s2, s3);
        LDB(1, s0, s1, s2, s3);
        SMM(1, s0, s1, s2, s3);
        EPO(1, s0, s1, s2, s3);
        LDB(2, s0, s1, s2, s3);
        SMM(2, s0, s1, s2, s3);
        EPO(2, s0, s1, s2, s3);
        LDB(3, s0, s1, s2, s3);
        SMM(3, s0, s1, s2, s3);
        EPO(3, s0, s1, s2, s3);

        ee64 -= 2;
        __syncthreads();   // drains staged global_load_lds for kt+1 too
    }

#undef LDB
#undef SMM
#undef EPO

    // epilogue: reduce l across q-groups; O^T lane (q,n): query = i0+16qt+n,
    // d = 16u+4q+r -> att2 A-frag
    for (int qt = 0; qt < 4; ++qt) {
        float ls = lsum[qt];
        ls += __shfl_xor(ls, 16, 64);
        ls += __shfl_xor(ls, 32, 64);
        float inv = 1.0f / ls;
        int pt = ti0 + qt;
        for (int u = 0; u < 4; ++u) {
            int kcA = 2 * h + (u >> 1);
            int q2 = 2 * (u & 1) + (q >> 1);
            uint2 pk;
            pk.x = pkbf(o[qt][u][0] * inv, o[qt][u][1] * inv);
            pk.y = pkbf(o[qt][u][2] * inv, o[qt][u][3] * inv);
            size_t addr = ((size_t)((b * 64 + pt) * 16 + kcA) * 512)
                          + (q2 * 16 + n) * 8 + 4 * (q & 1);
            *(uint2*)&att2[addr] = pk;
        }
    }
}

// ---------------- output projection + residual ----------------
// (256,2): VGPR cap 128 >= ~100 demand. Was (256,4) = cap 64 -> spilled.
__global__ __launch_bounds__(256, 2) void out_gemm(const unsigned short* __restrict__ att2,
                                                   const unsigned short* __restrict__ w0f,
                                                   const float* __restrict__ x,
                                                   float* __restrict__ out) {
    int b = blockIdx.x, ct = blockIdx.y, ptb = blockIdx.z;
    int tid = threadIdx.x, wave = tid >> 6, lane = tid & 63, q = lane >> 4, n = lane & 15;
    int pos0 = ptb * 64 + wave * 16;
    int c0 = ct * 64;
    int pt = ptb * 4 + wave;
    const unsigned short* abase = att2 + (size_t)(b * 64 + pt) * 16 * 512 + lane * 8;
    const unsigned short* wbase = w0f + (size_t)(c0 >> 4) * 16 * 512 + lane * 8;
    floatx4 acc[4];
    for (int s = 0; s < 4; ++s) acc[s] = (floatx4){0.f, 0.f, 0.f, 0.f};
    for (int g = 0; g < 4; ++g) {
        bf16x8 af[4], bfr[4][4];
        for (int k2 = 0; k2 < 4; ++k2) af[k2] = ldfrag(abase + (g * 4 + k2) * 512);
        for (int s = 0; s < 4; ++s)
            for (int k2 = 0; k2 < 4; ++k2)
                bfr[s][k2] = ldfrag(wbase + (s * 16 + g * 4 + k2) * 512);
        for (int k2 = 0; k2 < 4; ++k2)
            for (int s = 0; s < 4; ++s)
                acc[s] = __builtin_amdgcn_mfma_f32_16x16x32_bf16(af[k2], bfr[s][k2], acc[s], 0, 0, 0);
    }
    int p0q = pos0 + 4 * q;
    for (int s = 0; s < 4; ++s) {
        int c = c0 + 16 * s + n;
        size_t idx = ((size_t)b * CIN + c) * SEQ + p0q;
        floatx4 res = *(const floatx4*)&x[idx];
        floatx4 v = acc[s] + res;
        *(floatx4*)&out[idx] = v;
    }
}

// ---------------- launch ----------------
extern "C" void kernel_launch(void* const* d_in, const int* in_sizes, int n_in,
                              void* d_out, int out_size, void* d_ws, size_t ws_size,
                              hipStream_t stream) {
    const float* x  = (const float*)d_in[0];
    const float* Wq = (const float*)d_in[1];
    const float* Wk = (const float*)d_in[2];
    const float* Wv = (const float*)d_in[3];
    const float* R  = (const float*)d_in[4];
    const float* W0 = (const float*)d_in[5];
    float* out = (float*)d_out;

    char* ws = (char*)d_ws;
    size_t off = 0;
    unsigned short* Qt   = (unsigned short*)(ws + off); off += (size_t)NB * NH * SEQ * DKH * 2;
    unsigned short* Kf   = (unsigned short*)(ws + off); off += (size_t)NB * NH * SEQ * DKH * 2;
    unsigned short* Vf   = (unsigned short*)(ws + off); off += (size_t)NB * NH * SEQ * DKH * 2;
    unsigned short* att2 = (unsigned short*)(ws + off); off += (size_t)NB * SEQ * HDIM * 2;
    unsigned short* xt2  = (unsigned short*)(ws + off); off += (size_t)NB * SEQ * CIN * 2;
    unsigned short* w2   = (unsigned short*)(ws + off); off += (size_t)1536 * 128 * 2;
    unsigned short* w0f  = (unsigned short*)(ws + off); off += (size_t)128 * 512 * 2;
    float* biasQ4 = (float*)(ws + off); off += (size_t)NH * 32 * 32 * 4 * 4;   // 128 KB
    (void)ws_size; (void)in_sizes; (void)n_in; (void)out_size;

    prep_all<<<2080, 256, 0, stream>>>(Wq, Wk, Wv, W0, R, x, w2, w0f, biasQ4, xt2);
    qkv_gemm<<<dim3(NB, 24, 16), 256, 0, stream>>>(xt2, w2, Qt, Kf, Vf);
    attn_kernel<<<NB * NH * 4, 256, 0, stream>>>(Qt, Kf, Vf, biasQ4, att2);
    out_gemm<<<dim3(NB, 2, 16), 256, 0, stream>>>(att2, w0f, x, out);
}

// Round 9
// 192.013 us; speedup vs baseline: 2.4987x; 1.0911x over previous
//
#include <hip/hip_runtime.h>

// CvT block, MI355X bf16-MFMA implementation.
// B=32, C=128, L=32 (seq=1024), H=8, DK=64, HD=512, NLAYER=4.
// R19: GEMM shared-operand LDS staging. In qkv_gemm/out_gemm the shared
// fragment tile (x-tile for QK rows, w-tile for V rows, w0f g-slices in
// out_gemm) was loaded redundantly by all 4 waves from global (4x traffic,
// 16-64 long-latency loads per wave at 2 blocks/CU). Now staged once per
// block via g2l16 into LDS; per-k fragments stream from LDS (reg demand
// ~65-70 -> launch_bounds(256,3) feasible, 12 waves/CU). Attn/prep = R18
// exactly (attn 81us best-measured: Q4 bias table, 4qt/wave, dbuf,(256,2)).

#define NB   32
#define NH   8
#define SEQ  1024
#define DKH  64
#define HDIM 512
#define CIN  128

// 0.125 * log2(e): folded into Wq and bias so scores are in exp2 domain.
#define SCL 0.18033688011112042f

typedef __bf16 bf16x8 __attribute__((ext_vector_type(8)));
typedef float floatx4 __attribute__((ext_vector_type(4)));
typedef unsigned short u16x8 __attribute__((ext_vector_type(8)));
typedef unsigned int uintx4 __attribute__((ext_vector_type(4)));

__device__ __forceinline__ unsigned short f2bf(float f) {
    union { float f; unsigned int u; } c; c.f = f;
    unsigned int u = c.u;
    return (unsigned short)((u + 0x7fffu + ((u >> 16) & 1u)) >> 16); // RNE
}
__device__ __forceinline__ bf16x8 ldfrag(const unsigned short* p) {
    u16x8 v = *reinterpret_cast<const u16x8*>(p);
    return __builtin_bit_cast(bf16x8, v);
}
// pack two f32 -> two RNE bf16; 'a' lands in the LOW short.
__device__ __forceinline__ unsigned int pkbf(float a, float b) {
    unsigned int ua = __builtin_bit_cast(unsigned int, a);
    unsigned int ub = __builtin_bit_cast(unsigned int, b);
    ua += 0x7fffu + ((ua >> 16) & 1u);
    ub += 0x7fffu + ((ub >> 16) & 1u);
    return __builtin_amdgcn_perm(ub, ua, 0x07060302u);
}
// truncation pack (P>0): one v_perm, no rounding adds.
__device__ __forceinline__ unsigned int pkbf_t(float a, float b) {
    return __builtin_amdgcn_perm(__builtin_bit_cast(unsigned int, b),
                                 __builtin_bit_cast(unsigned int, a), 0x07060302u);
}
// async global->LDS, 16B per lane; LDS dest = wave-uniform base + lane*16.
__device__ __forceinline__ void g2l16(const void* g, void* l) {
    __builtin_amdgcn_global_load_lds((const __attribute__((address_space(1))) void*)g,
                                     (__attribute__((address_space(3))) void*)l, 16, 0, 0);
}

// Fragment-order storage: 512-elem block = one wave fragment [lane][j].
// Kf (A-frag, m=key): frag (s,c): lane (q,n) j <-> K[key=16s+n][d=32c+8q+j]
// Vf (A-frag, m=d, permuted k): frag (u,c): lane (q,n) jj <->
//     V[key = 32c+16(jj>>2)+4q+(jj&3)][d=16u+n]   (matches P^T pack order)

// ---------------- merged prep: bias Q4 table + weight casts + x transpose ----------------
// bids [0, 32): biasQ4[h][dxx][st][r] = R[h][dxx][(32-st-r)&31] * SCL
//   (pre-grouped float4 circulant rows; bias C-frag = Q4[dxx][st]).
// bids [32, 1056): weight casts; Wq scaled by SCL (exp2 domain).
// bids [1056, 2080): xt2 = x transposed+scaled into B/A fragment order.
__global__ __launch_bounds__(256) void prep_all(const float* __restrict__ Wq,
                                                const float* __restrict__ Wk,
                                                const float* __restrict__ Wv,
                                                const float* __restrict__ W0,
                                                const float* __restrict__ R,
                                                const float* __restrict__ x,
                                                unsigned short* __restrict__ w2,
                                                unsigned short* __restrict__ w0f,
                                                float* __restrict__ biasQ4,
                                                unsigned short* __restrict__ xt2) {
    __shared__ float lds[64 * 65];
    int bid = blockIdx.x;
    if (bid < 32) {
        int idx4 = bid * 256 + threadIdx.x;            // [0, 8192) float4 slots
        int st = idx4 & 31, dxx = (idx4 >> 5) & 31, h = idx4 >> 10;
        const float* Rh = R + (h << 10) + (dxx << 5);
        floatx4 v;
        for (int r = 0; r < 4; ++r) v[r] = Rh[(32 - st - r) & 31] * SCL;
        *(floatx4*)&biasQ4[(size_t)idx4 * 4] = v;
    } else if (bid < 1056) {
        int idx = (bid - 32) * 256 + threadIdx.x;      // [0, 262144)
        if (idx < 196608) {
            int row = idx >> 7, col = idx & 127;
            float v;
            if (row < 512)       v = Wq[idx] * SCL;
            else if (row < 1024) v = Wk[idx - 65536];
            else                 v = Wv[idx - 131072];
            int rt = row >> 4, nr = row & 15, kc = col >> 5, qc = (col & 31) >> 3, jc = col & 7;
            w2[((rt * 4 + kc) * 512) + (qc * 16 + nr) * 8 + jc] = f2bf(v);
        } else {
            int idx2 = idx - 196608;
            int row = idx2 >> 9, col = idx2 & 511;
            int rt = row >> 4, nr = row & 15, kcA = col >> 5, qc = (col & 31) >> 3, jc = col & 7;
            w0f[((rt * 16 + kcA) * 512) + (qc * 16 + nr) * 8 + jc] = f2bf(W0[idx2]);
        }
    } else {
        int r = bid - 1056;                            // [0, 1024)
        int b = r & 31, yy = (r >> 5) & 1, zz = r >> 6;
        int c0 = yy * 64, p0 = zz * 64;
        int t = threadIdx.x, tr = t >> 6, tc = t & 63;
        const float inv_layer = 0.44721359549995793f;  // 1/sqrt(5)
        for (int rr = 0; rr < 16; ++rr) {
            int cl = rr * 4 + tr;
            lds[cl * 65 + tc] = x[(b * CIN + c0 + cl) * SEQ + p0 + tc];
        }
        __syncthreads();
        for (int rr = 0; rr < 16; ++rr) {
            int pl = rr * 4 + tr;
            int pos = p0 + pl, c = c0 + tc;
            int pt = pos >> 4, np = pos & 15, kc = c >> 5, qc = (c & 31) >> 3, jc = c & 7;
            xt2[((size_t)((b * 64 + pt) * 4 + kc) * 512) + (qc * 16 + np) * 8 + jc] =
                f2bf(lds[tc * 65 + pl] * inv_layer);
        }
    }
}

// ---------------- fused QKV projection (shared operand staged in LDS) ----------------
// y<16: shared = x tile (16 frags, wave-invariant) -> LDS; af = per-wave w rows.
// y>=16: shared = w tile (16 frags) -> LDS; af = per-wave x pos-tile.
// Per-kc streaming from LDS keeps regs ~70 -> (256,3), 12 waves/CU.
__global__ __launch_bounds__(256, 3) void qkv_gemm(const unsigned short* __restrict__ xt2,
                                                   const unsigned short* __restrict__ w2,
                                                   unsigned short* __restrict__ Qt,
                                                   unsigned short* __restrict__ Kf,
                                                   unsigned short* __restrict__ Vf) {
    __shared__ alignas(16) unsigned short lds_s[16 * 512];   // 16 KB shared tile
    int b = blockIdx.x, y = blockIdx.y, zt = blockIdx.z;
    int tid = threadIdx.x, wave = tid >> 6, lane = tid & 63, q = lane >> 4, n = lane & 15;
    floatx4 acc[4];
    for (int s = 0; s < 4; ++s) acc[s] = (floatx4){0.f, 0.f, 0.f, 0.f};
    bf16x8 af[4];

    if (y < 16) {
        // stage shared x tile (b, zt): frags f = s*4+kc
        const unsigned short* xsrc = xt2 + (size_t)(b * 64 + zt * 4) * 4 * 512;
        for (int i = 0; i < 4; ++i) {
            int f = wave * 4 + i;
            g2l16(xsrc + f * 512 + lane * 8, &lds_s[f * 512]);
        }
        int rt = y * 4 + wave;                       // per-wave w-row tile
        const unsigned short* wbase = w2 + (size_t)rt * 4 * 512 + lane * 8;
        for (int kc = 0; kc < 4; ++kc) af[kc] = ldfrag(wbase + kc * 512);
        __syncthreads();                             // drains g2l16 + af
#pragma unroll
        for (int kc = 0; kc < 4; ++kc) {
            bf16x8 b0 = ldfrag(&lds_s[(0 * 4 + kc) * 512 + lane * 8]);
            bf16x8 b1 = ldfrag(&lds_s[(1 * 4 + kc) * 512 + lane * 8]);
            bf16x8 b2 = ldfrag(&lds_s[(2 * 4 + kc) * 512 + lane * 8]);
            bf16x8 b3 = ldfrag(&lds_s[(3 * 4 + kc) * 512 + lane * 8]);
            acc[0] = __builtin_amdgcn_mfma_f32_16x16x32_bf16(af[kc], b0, acc[0], 0, 0, 0);
            acc[1] = __builtin_amdgcn_mfma_f32_16x16x32_bf16(af[kc], b1, acc[1], 0, 0, 0);
            acc[2] = __builtin_amdgcn_mfma_f32_16x16x32_bf16(af[kc], b2, acc[2], 0, 0, 0);
            acc[3] = __builtin_amdgcn_mfma_f32_16x16x32_bf16(af[kc], b3, acc[3], 0, 0, 0);
        }
        int wrow0 = y * 64 + wave * 16;
        int pos0 = zt * 64;
        if (y < 8) {
            int h = wrow0 >> 6;
            int d0 = (wrow0 & 63) + 4 * q;
            for (int s = 0; s < 4; ++s) {
                uint2 pk;
                pk.x = pkbf(acc[s][0], acc[s][1]);
                pk.y = pkbf(acc[s][2], acc[s][3]);
                int pos = pos0 + 16 * s + n;
                *(uint2*)&Qt[((size_t)(b * NH + h) * SEQ + pos) * DKH + d0] = pk;
            }
        } else {
            // K: d = wave*16+4q+r (regs), key = 16s+n. A-frag store.
            int h = (wrow0 >> 6) - 8;
            int bh = b * NH + h;
            int cd = wave >> 1;
            int qk = 2 * (wave & 1) + (q >> 1);
            int jk = 4 * (q & 1);
            for (int s = 0; s < 4; ++s) {
                uint2 pk;
                pk.x = pkbf(acc[s][0], acc[s][1]);
                pk.y = pkbf(acc[s][2], acc[s][3]);
                size_t addr = ((size_t)(bh * 16 + zt) * 8 + s * 2 + cd) * 512
                              + (qk * 16 + n) * 8 + jk;
                *(uint2*)&Kf[addr] = pk;
            }
        }
    } else {
        // stage shared w tile (V rows rtv0..rtv0+3): frags f = s*4+kc
        const unsigned short* wsrc = w2 + (size_t)(64 + (y - 16) * 4) * 4 * 512;
        for (int i = 0; i < 4; ++i) {
            int f = wave * 4 + i;
            g2l16(wsrc + f * 512 + lane * 8, &lds_s[f * 512]);
        }
        int pt = zt * 4 + wave;                      // per-wave pos tile
        const unsigned short* xbase = xt2 + (size_t)(b * 64 + pt) * 4 * 512 + lane * 8;
        for (int kc = 0; kc < 4; ++kc) af[kc] = ldfrag(xbase + kc * 512);
        __syncthreads();
#pragma unroll
        for (int kc = 0; kc < 4; ++kc) {
            bf16x8 b0 = ldfrag(&lds_s[(0 * 4 + kc) * 512 + lane * 8]);
            bf16x8 b1 = ldfrag(&lds_s[(1 * 4 + kc) * 512 + lane * 8]);
            bf16x8 b2 = ldfrag(&lds_s[(2 * 4 + kc) * 512 + lane * 8]);
            bf16x8 b3 = ldfrag(&lds_s[(3 * 4 + kc) * 512 + lane * 8]);
            acc[0] = __builtin_amdgcn_mfma_f32_16x16x32_bf16(af[kc], b0, acc[0], 0, 0, 0);
            acc[1] = __builtin_amdgcn_mfma_f32_16x16x32_bf16(af[kc], b1, acc[1], 0, 0, 0);
            acc[2] = __builtin_amdgcn_mfma_f32_16x16x32_bf16(af[kc], b2, acc[2], 0, 0, 0);
            acc[3] = __builtin_amdgcn_mfma_f32_16x16x32_bf16(af[kc], b3, acc[3], 0, 0, 0);
        }
        // V: key = wave*16+4q+r (regs) -> Vf A-frag with PV k-permutation.
        int vrow0 = (y - 16) * 64;
        int cj = wave >> 1;
        int jj0 = 4 * (wave & 1);
        for (int s = 0; s < 4; ++s) {
            int vrow = vrow0 + 16 * s + n;
            int h = vrow >> 6, d = vrow & 63;
            int u = d >> 4, nl = d & 15;
            uint2 pk;
            pk.x = pkbf(acc[s][0], acc[s][1]);
            pk.y = pkbf(acc[s][2], acc[s][3]);
            size_t addr = ((size_t)((b * NH + h) * 16 + zt) * 8 + u * 2 + cj) * 512
                          + (q * 16 + nl) * 8 + jj0;
            *(uint2*)&Vf[addr] = pk;
        }
    }
}

// ---------------- attention (4 qt/wave, 2 blocks/CU — R18 proven, untouched) ----------------
__global__ __launch_bounds__(256, 2) void attn_kernel(const unsigned short* __restrict__ Qt,
                                                      const unsigned short* __restrict__ Kf,
                                                      const unsigned short* __restrict__ Vf,
                                                      const float* __restrict__ biasQ4,
                                                      unsigned short* __restrict__ att2) {
    __shared__ alignas(16) unsigned short lds_k[2][8 * 512];   // 16 KB
    __shared__ alignas(16) unsigned short lds_v[2][8 * 512];   // 16 KB
    __shared__ alignas(16) float lds_bQ[4096];                 // 16 KB Q4 table

    int gid = blockIdx.x;
    int bh = gid & 255, qb = gid >> 8;                // qb in [0,4)
    int b = bh >> 3, h = bh & 7;
    int tid = threadIdx.x, wave = tid >> 6, lane = tid & 63, q = lane >> 4, n = lane & 15;
    int i0 = qb * 256 + wave * 64;
    int ti0 = i0 >> 4;

    const unsigned short* qbase = Qt + (size_t)bh * SEQ * DKH;
    const unsigned short* kft = Kf + (size_t)bh * 16 * 4096;
    const unsigned short* vft = Vf + (size_t)bh * 16 * 4096;
    int off0 = wave * 512;

    // ---- prologue: per-head Q4 table -> LDS; stage K/V tile 0 ----
    {
        const float* bQg = biasQ4 + (size_t)h * 4096;
        for (int i = 0; i < 4; ++i) {
            int fo = i * 1024 + wave * 256;           // wave-uniform float offset
            g2l16(bQg + fo + lane * 4, &lds_bQ[fo]);
        }
        g2l16(kft + off0 + lane * 8,        &lds_k[0][off0]);
        g2l16(kft + 2048 + off0 + lane * 8, &lds_k[0][2048 + off0]);
        g2l16(vft + off0 + lane * 8,        &lds_v[0][off0]);
        g2l16(vft + 2048 + off0 + lane * 8, &lds_v[0][2048 + off0]);
    }

    // Q as B-fragments: lane (q,n): query = i0+16qt+n, d = c*32+8q+j
    bf16x8 aq[4][2];
    for (int qt = 0; qt < 4; ++qt)
        for (int c = 0; c < 2; ++c)
            aq[qt][c] = ldfrag(qbase + (i0 + 16 * qt + n) * DKH + c * 32 + q * 8);

    floatx4 o[4][4];
    float lsum[4] = {0.f, 0.f, 0.f, 0.f};
    for (int qt = 0; qt < 4; ++qt)
        for (int u = 0; u < 4; ++u) o[qt][u] = (floatx4){0.f, 0.f, 0.f, 0.f};

    // bias gather: sv_s = Q4[dxx][st] (float4 = one b128).
    //   dxx = (ee + (qt>>1) - (s>>1)) & 31, ee = qb*8 + 2*wave - 2*kt;
    //   st = st0 if (s&1)==(qt&1) else st1 (per-lane column starts).
    int st0_4 = ((4 * q - n) & 31) * 4;
    int st1_4 = (((4 * q - n) + 16) & 31) * 4;
    int ee64 = qb * 8 + 2 * wave + 256;               // stays positive over kt

    __syncthreads();

// bias C-init for query tile qt (3 dxx bases: eh = ee+(qt>>1), el = eh-1)
#define LDB(qt, s0, s1, s2, s3) do {                                          \
        int eh_ = ee64 + ((qt) >> 1);                                         \
        int dh_ = (eh_ & 31) << 7;                                            \
        int dl_ = ((eh_ - 1) & 31) << 7;                                      \
        int sa_ = ((qt) & 1) ? st1_4 : st0_4;                                 \
        int sb_ = ((qt) & 1) ? st0_4 : st1_4;                                 \
        s0 = *(const floatx4*)&lds_bQ[dh_ + sa_];                             \
        s1 = *(const floatx4*)&lds_bQ[dh_ + sb_];                             \
        s2 = *(const floatx4*)&lds_bQ[dl_ + sa_];                             \
        s3 = *(const floatx4*)&lds_bQ[dl_ + sb_];                             \
    } while (0)

// S^T MFMA cluster for query tile qt
#define SMM(qt, s0, s1, s2, s3) do {                                          \
        s0 = __builtin_amdgcn_mfma_f32_16x16x32_bf16(kf2[0][0], aq[qt][0], s0, 0, 0, 0); \
        s0 = __builtin_amdgcn_mfma_f32_16x16x32_bf16(kf2[0][1], aq[qt][1], s0, 0, 0, 0); \
        s1 = __builtin_amdgcn_mfma_f32_16x16x32_bf16(kf2[1][0], aq[qt][0], s1, 0, 0, 0); \
        s1 = __builtin_amdgcn_mfma_f32_16x16x32_bf16(kf2[1][1], aq[qt][1], s1, 0, 0, 0); \
        s2 = __builtin_amdgcn_mfma_f32_16x16x32_bf16(kf2[2][0], aq[qt][0], s2, 0, 0, 0); \
        s2 = __builtin_amdgcn_mfma_f32_16x16x32_bf16(kf2[2][1], aq[qt][1], s2, 0, 0, 0); \
        s3 = __builtin_amdgcn_mfma_f32_16x16x32_bf16(kf2[3][0], aq[qt][0], s3, 0, 0, 0); \
        s3 = __builtin_amdgcn_mfma_f32_16x16x32_bf16(kf2[3][1], aq[qt][1], s3, 0, 0, 0); \
    } while (0)

// exp2 -> pack -> l partial -> O MFMA cluster for query tile qt
#define EPO(qt, s0, s1, s2, s3) do {                                          \
        floatx4 e0_, e1_, e2_, e3_;                                           \
        for (int r_ = 0; r_ < 4; ++r_) {                                      \
            e0_[r_] = __builtin_amdgcn_exp2f(s0[r_]);                         \
            e1_[r_] = __builtin_amdgcn_exp2f(s1[r_]);                         \
            e2_[r_] = __builtin_amdgcn_exp2f(s2[r_]);                         \
            e3_[r_] = __builtin_amdgcn_exp2f(s3[r_]);                         \
        }                                                                     \
        uintx4 pu0_, pu1_;                                                    \
        pu0_[0] = pkbf_t(e0_[0], e0_[1]);                                     \
        pu0_[1] = pkbf_t(e0_[2], e0_[3]);                                     \
        pu0_[2] = pkbf_t(e1_[0], e1_[1]);                                     \
        pu0_[3] = pkbf_t(e1_[2], e1_[3]);                                     \
        pu1_[0] = pkbf_t(e2_[0], e2_[1]);                                     \
        pu1_[1] = pkbf_t(e2_[2], e2_[3]);                                     \
        pu1_[2] = pkbf_t(e3_[0], e3_[1]);                                     \
        pu1_[3] = pkbf_t(e3_[2], e3_[3]);                                     \
        bf16x8 pf0_ = __builtin_bit_cast(bf16x8, pu0_);                       \
        bf16x8 pf1_ = __builtin_bit_cast(bf16x8, pu1_);                       \
        floatx4 es_ = (e0_ + e1_) + (e2_ + e3_);                              \
        lsum[qt] += (es_[0] + es_[1]) + (es_[2] + es_[3]);                    \
        o[qt][0] = __builtin_amdgcn_mfma_f32_16x16x32_bf16(vf2[0][0], pf0_, o[qt][0], 0, 0, 0); \
        o[qt][0] = __builtin_amdgcn_mfma_f32_16x16x32_bf16(vf2[0][1], pf1_, o[qt][0], 0, 0, 0); \
        o[qt][1] = __builtin_amdgcn_mfma_f32_16x16x32_bf16(vf2[1][0], pf0_, o[qt][1], 0, 0, 0); \
        o[qt][1] = __builtin_amdgcn_mfma_f32_16x16x32_bf16(vf2[1][1], pf1_, o[qt][1], 0, 0, 0); \
        o[qt][2] = __builtin_amdgcn_mfma_f32_16x16x32_bf16(vf2[2][0], pf0_, o[qt][2], 0, 0, 0); \
        o[qt][2] = __builtin_amdgcn_mfma_f32_16x16x32_bf16(vf2[2][1], pf1_, o[qt][2], 0, 0, 0); \
        o[qt][3] = __builtin_amdgcn_mfma_f32_16x16x32_bf16(vf2[3][0], pf0_, o[qt][3], 0, 0, 0); \
        o[qt][3] = __builtin_amdgcn_mfma_f32_16x16x32_bf16(vf2[3][1], pf1_, o[qt][3], 0, 0, 0); \
    } while (0)

    for (int kt = 0; kt < 16; ++kt) {
        int cur = kt & 1;

        // async stage next K/V tile
        if (kt < 15) {
            const unsigned short* kg = kft + (kt + 1) * 4096;
            const unsigned short* vg = vft + (kt + 1) * 4096;
            unsigned short* dk = &lds_k[cur ^ 1][0];
            unsigned short* dv = &lds_v[cur ^ 1][0];
            g2l16(kg + off0 + lane * 8,        dk + off0);
            g2l16(kg + 2048 + off0 + lane * 8, dk + 2048 + off0);
            g2l16(vg + off0 + lane * 8,        dv + off0);
            g2l16(vg + 2048 + off0 + lane * 8, dv + 2048 + off0);
        }

        // K,V fragments (shared across the 4 query tiles)
        bf16x8 kf2[4][2], vf2[4][2];
#pragma unroll
        for (int s = 0; s < 4; ++s)
#pragma unroll
            for (int c = 0; c < 2; ++c) {
                kf2[s][c] = ldfrag(&lds_k[cur][(s * 2 + c) * 512 + lane * 8]);
                vf2[s][c] = ldfrag(&lds_v[cur][(s * 2 + c) * 512 + lane * 8]);
            }

        floatx4 s0, s1, s2, s3;
        LDB(0, s0, s1, s2, s3);
        SMM(0, s0, s1, s2, s3);
        EPO(0, s0, s1, s2, s3);
        LDB(1, s0, s1, s2, s3);
        SMM(1, s0, s1, s2, s3);
        EPO(1, s0, s1, s2, s3);
        LDB(2, s0, s1, s2, s3);
        SMM(2, s0, s1, s2, s3);
        EPO(2, s0, s1, s2, s3);
        LDB(3, s0, s1, s2, s3);
        SMM(3, s0, s1, s2, s3);
        EPO(3, s0, s1, s2, s3);

        ee64 -= 2;
        __syncthreads();   // drains staged global_load_lds for kt+1 too
    }

#undef LDB
#undef SMM
#undef EPO

    // epilogue: reduce l across q-groups; O^T lane (q,n): query = i0+16qt+n,
    // d = 16u+4q+r -> att2 A-frag
    for (int qt = 0; qt < 4; ++qt) {
        float ls = lsum[qt];
        ls += __shfl_xor(ls, 16, 64);
        ls += __shfl_xor(ls, 32, 64);
        float inv = 1.0f / ls;
        int pt = ti0 + qt;
        for (int u = 0; u < 4; ++u) {
            int kcA = 2 * h + (u >> 1);
            int q2 = 2 * (u & 1) + (q >> 1);
            uint2 pk;
            pk.x = pkbf(o[qt][u][0] * inv, o[qt][u][1] * inv);
            pk.y = pkbf(o[qt][u][2] * inv, o[qt][u][3] * inv);
            size_t addr = ((size_t)((b * 64 + pt) * 16 + kcA) * 512)
                          + (q2 * 16 + n) * 8 + 4 * (q & 1);
            *(uint2*)&att2[addr] = pk;
        }
    }
}

// ---------------- output projection + residual (w0f g-slices staged in LDS) ----------------
// wbase was wave-invariant: each wave loaded the same 64 frags from global
// (4x redundant). Now double-buffered 16KB g-slices staged via g2l16.
__global__ __launch_bounds__(256, 3) void out_gemm(const unsigned short* __restrict__ att2,
                                                   const unsigned short* __restrict__ w0f,
                                                   const float* __restrict__ x,
                                                   float* __restrict__ out) {
    __shared__ alignas(16) unsigned short lds_w[2][16 * 512];  // 2 x 16 KB
    int b = blockIdx.x, ct = blockIdx.y, ptb = blockIdx.z;
    int tid = threadIdx.x, wave = tid >> 6, lane = tid & 63, q = lane >> 4, n = lane & 15;
    int pos0 = ptb * 64 + wave * 16;
    int c0 = ct * 64;
    int pt = ptb * 4 + wave;
    const unsigned short* abase = att2 + (size_t)(b * 64 + pt) * 16 * 512 + lane * 8;
    const unsigned short* wsrc = w0f + (size_t)(c0 >> 4) * 16 * 512;
    floatx4 acc[4];
    for (int s = 0; s < 4; ++s) acc[s] = (floatx4){0.f, 0.f, 0.f, 0.f};

    // stage g=0 slice: frag (s=wave, k2) -> lds slot (wave*4+k2)
    for (int k2 = 0; k2 < 4; ++k2)
        g2l16(wsrc + (wave * 16 + k2) * 512 + lane * 8, &lds_w[0][(wave * 4 + k2) * 512]);
    __syncthreads();

    for (int g = 0; g < 4; ++g) {
        int buf = g & 1;
        if (g < 3) {
            for (int k2 = 0; k2 < 4; ++k2)
                g2l16(wsrc + (wave * 16 + (g + 1) * 4 + k2) * 512 + lane * 8,
                      &lds_w[buf ^ 1][(wave * 4 + k2) * 512]);
        }
        bf16x8 af[4];
        for (int k2 = 0; k2 < 4; ++k2) af[k2] = ldfrag(abase + (g * 4 + k2) * 512);
#pragma unroll
        for (int k2 = 0; k2 < 4; ++k2) {
            bf16x8 b0 = ldfrag(&lds_w[buf][(0 * 4 + k2) * 512 + lane * 8]);
            bf16x8 b1 = ldfrag(&lds_w[buf][(1 * 4 + k2) * 512 + lane * 8]);
            bf16x8 b2 = ldfrag(&lds_w[buf][(2 * 4 + k2) * 512 + lane * 8]);
            bf16x8 b3 = ldfrag(&lds_w[buf][(3 * 4 + k2) * 512 + lane * 8]);
            acc[0] = __builtin_amdgcn_mfma_f32_16x16x32_bf16(af[k2], b0, acc[0], 0, 0, 0);
            acc[1] = __builtin_amdgcn_mfma_f32_16x16x32_bf16(af[k2], b1, acc[1], 0, 0, 0);
            acc[2] = __builtin_amdgcn_mfma_f32_16x16x32_bf16(af[k2], b2, acc[2], 0, 0, 0);
            acc[3] = __builtin_amdgcn_mfma_f32_16x16x32_bf16(af[k2], b3, acc[3], 0, 0, 0);
        }
        __syncthreads();   // drains next-slice staging; separates buf reuse
    }

    int p0q = pos0 + 4 * q;
    for (int s = 0; s < 4; ++s) {
        int c = c0 + 16 * s + n;
        size_t idx = ((size_t)b * CIN + c) * SEQ + p0q;
        floatx4 res = *(const floatx4*)&x[idx];
        floatx4 v = acc[s] + res;
        *(floatx4*)&out[idx] = v;
    }
}

// ---------------- launch ----------------
extern "C" void kernel_launch(void* const* d_in, const int* in_sizes, int n_in,
                              void* d_out, int out_size, void* d_ws, size_t ws_size,
                              hipStream_t stream) {
    const float* x  = (const float*)d_in[0];
    const float* Wq = (const float*)d_in[1];
    const float* Wk = (const float*)d_in[2];
    const float* Wv = (const float*)d_in[3];
    const float* R  = (const float*)d_in[4];
    const float* W0 = (const float*)d_in[5];
    float* out = (float*)d_out;

    char* ws = (char*)d_ws;
    size_t off = 0;
    unsigned short* Qt   = (unsigned short*)(ws + off); off += (size_t)NB * NH * SEQ * DKH * 2;
    unsigned short* Kf   = (unsigned short*)(ws + off); off += (size_t)NB * NH * SEQ * DKH * 2;
    unsigned short* Vf   = (unsigned short*)(ws + off); off += (size_t)NB * NH * SEQ * DKH * 2;
    unsigned short* att2 = (unsigned short*)(ws + off); off += (size_t)NB * SEQ * HDIM * 2;
    unsigned short* xt2  = (unsigned short*)(ws + off); off += (size_t)NB * SEQ * CIN * 2;
    unsigned short* w2   = (unsigned short*)(ws + off); off += (size_t)1536 * 128 * 2;
    unsigned short* w0f  = (unsigned short*)(ws + off); off += (size_t)128 * 512 * 2;
    float* biasQ4 = (float*)(ws + off); off += (size_t)NH * 32 * 32 * 4 * 4;   // 128 KB
    (void)ws_size; (void)in_sizes; (void)n_in; (void)out_size;

    prep_all<<<2080, 256, 0, stream>>>(Wq, Wk, Wv, W0, R, x, w2, w0f, biasQ4, xt2);
    qkv_gemm<<<dim3(NB, 24, 16), 256, 0, stream>>>(xt2, w2, Qt, Kf, Vf);
    attn_kernel<<<NB * NH * 4, 256, 0, stream>>>(Qt, Kf, Vf, biasQ4, att2);
    out_gemm<<<dim3(NB, 2, 16), 256, 0, stream>>>(att2, w0f, x, out);
}